// Round 2
// baseline (439.760 us; speedup 1.0000x reference)
//
#include <hip/hip_runtime.h>

// x: [16, 512, 64, 64] fp32, memory: [1024, 512] fp32
// recon: [16, 512, 64, 64] fp32, match: [16, 64, 64] fp32
#define C_DIM 512
#define K_MEM 1024

typedef __attribute__((ext_vector_type(8))) short short8;     // 8 bf16
typedef __attribute__((ext_vector_type(16))) float f32x16;
typedef __attribute__((ext_vector_type(4))) unsigned int u32x4;

#define WAITV2() asm volatile("s_waitcnt vmcnt(2)" ::: "memory")
#define WAITV0() asm volatile("s_waitcnt vmcnt(0)" ::: "memory")
#define LGKM0()  asm volatile("s_waitcnt lgkmcnt(0)" ::: "memory")
#define BAR()    { asm volatile("" ::: "memory"); __builtin_amdgcn_s_barrier(); asm volatile("" ::: "memory"); }

__device__ __forceinline__ unsigned short f2bf(float f) {
    unsigned int u = __builtin_bit_cast(unsigned int, f);
    unsigned int r = (u + 0x7fffu + ((u >> 16) & 1u)) >> 16;  // RNE
    return (unsigned short)r;
}

__device__ __forceinline__ f32x16 mfma32(short8 a, short8 b, f32x16 c) {
    return __builtin_amdgcn_mfma_f32_32x32x16_bf16(a, b, c, 0, 0, 0);
}

__device__ __forceinline__ void gl_lds16(const void* g, void* l) {
    __builtin_amdgcn_global_load_lds(
        (const __attribute__((address_space(1))) unsigned int*)g,
        (__attribute__((address_space(3))) unsigned int*)l, 16, 0, 0);
}

// ---------------- prep 1: L2-normalize memory rows -> bf16 Mn[k][c] ----------------
__global__ __launch_bounds__(256)
void prep_norm(const float* __restrict__ mem, unsigned short* __restrict__ Mn) {
    int k = blockIdx.x, t = threadIdx.x;
    const float* row = mem + (size_t)k * C_DIM;
    float2 v = *reinterpret_cast<const float2*>(row + 2 * t);
    float ss = v.x * v.x + v.y * v.y;
#pragma unroll
    for (int off = 32; off >= 1; off >>= 1) ss += __shfl_xor(ss, off);
    __shared__ float wp[4];
    if ((t & 63) == 0) wp[t >> 6] = ss;
    __syncthreads();
    float tot = wp[0] + wp[1] + wp[2] + wp[3];
    float rn = 1.0f / fmaxf(sqrtf(tot), 1e-12f);
    unsigned int pk = (unsigned int)f2bf(v.x * rn) | ((unsigned int)f2bf(v.y * rn) << 16);
    *reinterpret_cast<unsigned int*>(Mn + (size_t)k * C_DIM + 2 * t) = pk;
}

// ---------------- prep 2: transpose Mn[k][c] -> MnT[c][k] ----------------
__global__ __launch_bounds__(256)
void prep_transpose(const unsigned short* __restrict__ Mn, unsigned short* __restrict__ MnT) {
    __shared__ unsigned short tl[64][72];
    int t = threadIdx.x;
    int bk = blockIdx.x & 15, bc = blockIdx.x >> 4;
    int k0 = bk * 64, c0 = bc * 64;
    {
        int kr = t >> 2, gc = (t & 3) * 16;
        const u32x4* src = reinterpret_cast<const u32x4*>(Mn + (size_t)(k0 + kr) * C_DIM + c0 + gc);
        u32x4 a = src[0], b = src[1];
        *reinterpret_cast<u32x4*>(&tl[kr][gc]) = a;
        *reinterpret_cast<u32x4*>(&tl[kr][gc + 8]) = b;
    }
    __syncthreads();
    {
        int cr = t >> 2, gk = (t & 3) * 16;
        unsigned int ow[8];
#pragma unroll
        for (int j = 0; j < 8; ++j)
            ow[j] = (unsigned int)tl[gk + 2 * j][cr] | ((unsigned int)tl[gk + 2 * j + 1][cr] << 16);
        unsigned int* dst = reinterpret_cast<unsigned int*>(MnT + (size_t)(c0 + cr) * K_MEM + k0 + gk);
#pragma unroll
        for (int j = 0; j < 8; ++j) dst[j] = ow[j];
    }
}

// Chunk schedule: q in [0,128): kt = q>>5, ph = q&31.
// ph<16 : GEMM1 chunk = Mn[kt*256 .. +256][ph*32 .. +32]  -> [256 rows][4 granules], swz gs = g ^ ((row>>1)&3)
// ph>=16: GEMM2 chunk = MnT[0..512][kt*256 + (ph-16)*16 ..+16] -> [512 rows][2 granules], no swz
__device__ __forceinline__ void issue_chunk(int q, char* stage,
        const unsigned short* __restrict__ Mn, const unsigned short* __restrict__ MnT,
        int wv, int lane) {
    if (q >= 128) return;
    const int kt = q >> 5, ph = q & 31;
    char* buf = stage + (q % 3) * 16384;
    if (ph < 16) {
#pragma unroll
        for (int j = 0; j < 2; ++j) {
            int G = (wv * 2 + j) * 64 + lane;
            int row = G >> 2, g = G & 3;
            int gs = g ^ ((row >> 1) & 3);
            const unsigned short* src = Mn + (size_t)(kt * 256 + row) * C_DIM + ph * 32 + gs * 8;
            gl_lds16(src, buf + (wv * 2 + j) * 1024);  // wave-uniform LDS base + lane*16
        }
    } else {
        const int ks = ph - 16;
#pragma unroll
        for (int j = 0; j < 2; ++j) {
            int G = (wv * 2 + j) * 64 + lane;
            int row = G >> 1, g = G & 1;
            const unsigned short* src = MnT + (size_t)row * K_MEM + kt * 256 + ks * 16 + g * 8;
            gl_lds16(src, buf + (wv * 2 + j) * 1024);
        }
    }
}

// ---------------- fused kernel ----------------
__global__ __launch_bounds__(512, 2)
void fused_attn(const float* __restrict__ x,
                const unsigned short* __restrict__ Mn,
                const unsigned short* __restrict__ MnT,
                float* __restrict__ recon,
                float* __restrict__ match) {
    __shared__ alignas(16) unsigned short Fn[64 * 512];   // XOR-swizzled granules per row
    __shared__ alignas(16) char stage[3 * 16384];          // triple-buffered DMA chunks
    __shared__ alignas(16) unsigned short Plds[64 * 256];  // exp(S) bf16, XOR-swizzled
    __shared__ float partS[4][64], partM[4][64];
    __shared__ float Zs[64], Ms[64], Zinv[64], rnormS[64];

    const int t = threadIdx.x;
    const int bid = blockIdx.x;            // b*64 + h
    const int b = bid >> 6, h = bid & 63;
    const int lane = t & 63, wv = t >> 6;  // 8 waves
    const int l31 = lane & 31, l5 = lane >> 5;
    const int nh = wv & 1, kq = wv >> 1;   // GEMM1 roles

    char* FnB = (char*)Fn;
    char* PldsB = (char*)Plds;

    // prologue: start DMA of chunks 0,1 (hidden under phase 0)
    issue_chunk(0, stage, Mn, MnT, wv, lane);
    issue_chunk(1, stage, Mn, MnT, wv, lane);

    // ---- phase 0: feature norms + swizzled bf16 tile into LDS ----
    {
        float* normpart = (float*)PldsB;   // overlay [64][10] in Plds (unused until kt0 softmax)
        const int w = lane, cg = wv;
        const float* xp = x + (size_t)b * 2097152 + (size_t)h * 64 + w;
        float ss = 0.f;
#pragma unroll 4
        for (int i = 0; i < 64; ++i) {
            float v = xp[(size_t)(cg * 64 + i) * 4096];
            ss += v * v;
        }
        normpart[w * 10 + cg] = ss;
        if (t < 64) { Zs[t] = 0.f; Ms[t] = -3.0e38f; }
        __syncthreads();
        if (t < 64) {
            float s = 0.f;
#pragma unroll
            for (int j = 0; j < 8; ++j) s += normpart[t * 10 + j];
            rnormS[t] = 1.0f / fmaxf(sqrtf(s), 1e-12f);
        }
        __syncthreads();
        float rn = rnormS[w];
        char* fnrow = FnB + w * 1024;
        int sw = (w & 7) << 4;
#pragma unroll 4
        for (int i = 0; i < 64; i += 2) {
            float v0 = xp[(size_t)(cg * 64 + i) * 4096] * rn;
            float v1 = xp[(size_t)(cg * 64 + i + 1) * 4096] * rn;
            unsigned int pk = (unsigned int)f2bf(v0) | ((unsigned int)f2bf(v1) << 16);
            int col = cg * 64 + i;
            *(unsigned int*)(fnrow + (((col >> 3) << 4) ^ sw) + (col & 7) * 2) = pk;
        }
    }
    __syncthreads();  // Fn visible (full drain OK pre-loop; chunk0/1 landed anyway)

    f32x16 acc3[2][2];
#pragma unroll
    for (int i = 0; i < 2; ++i)
#pragma unroll
        for (int j = 0; j < 2; ++j)
#pragma unroll
            for (int r = 0; r < 16; ++r) acc3[i][j][r] = 0.f;

    const int rowa_off = (nh * 32 + l31) * 1024;  // Fn A-row byte offset
    const int swA = (l31 & 7) << 4;
    int q = 0, sl = 0;

    for (int kt = 0; kt < 4; ++kt) {
        f32x16 acc1[2];
#pragma unroll
        for (int j = 0; j < 2; ++j)
#pragma unroll
            for (int r = 0; r < 16; ++r) acc1[j][r] = 0.f;

        // ---- GEMM1: S[64n x 256k], 16 phases of 32c ----
        for (int cc = 0; cc < 16; ++cc) {
            if (q >= 126) { WAITV0(); } else { WAITV2(); }
            BAR();
            issue_chunk(q + 2, stage, Mn, MnT, wv, lane);
            char* buf = stage + sl * 16384;
#pragma unroll
            for (int s = 0; s < 2; ++s) {
                int cgr = cc * 4 + s * 2 + l5;
                short8 af = *(const short8*)(FnB + rowa_off + (((cgr << 4)) ^ swA));
#pragma unroll
                for (int jt = 0; jt < 2; ++jt) {
                    int rowb = kq * 64 + jt * 32 + l31;
                    int g = s * 2 + l5;
                    short8 bf = *(const short8*)(buf + rowb * 64 + ((g ^ ((rowb >> 1) & 3)) << 4));
                    acc1[jt] = mfma32(af, bf, acc1[jt]);
                }
            }
            ++q; sl = (sl == 2) ? 0 : sl + 1;
        }

        // ---- softmax: exp(S) (no max-sub needed: |S|<=1), row stats, P->Plds ----
        {
#pragma unroll
            for (int r = 0; r < 16; ++r) {
                float e0 = __expf(acc1[0][r]);
                float e1 = __expf(acc1[1][r]);
                float s = e0 + e1;
                float m = fmaxf(acc1[0][r], acc1[1][r]);
#pragma unroll
                for (int off = 1; off < 32; off <<= 1) {
                    s += __shfl_xor(s, off);
                    m = fmaxf(m, __shfl_xor(m, off));
                }
                int n = nh * 32 + 4 * l5 + (r & 3) + 8 * (r >> 2);
                char* prow = PldsB + n * 512;
                int swN = (n & 7) << 4;
                int k0 = kq * 64 + l31, k1 = k0 + 32;
                *(unsigned short*)(prow + (((k0 >> 3) << 4) ^ swN) + (k0 & 7) * 2) = f2bf(e0);
                *(unsigned short*)(prow + (((k1 >> 3) << 4) ^ swN) + (k1 & 7) * 2) = f2bf(e1);
                if (l31 == 0) { partS[kq][n] = s; partM[kq][n] = m; }
            }
            LGKM0();  // publish Plds/partS before next phase's barrier
        }

        // ---- GEMM2 (recon^T): 16 phases of 16k ----
        for (int ks = 0; ks < 16; ++ks) {
            if (q >= 126) { WAITV0(); } else { WAITV2(); }
            BAR();
            issue_chunk(q + 2, stage, Mn, MnT, wv, lane);
            if (ks == 0 && t < 64) {
                Zs[t] += partS[0][t] + partS[1][t] + partS[2][t] + partS[3][t];
                Ms[t] = fmaxf(Ms[t], fmaxf(fmaxf(partM[0][t], partM[1][t]),
                                            fmaxf(partM[2][t], partM[3][t])));
            }
            char* buf = stage + sl * 16384;
            short8 bp[2];
#pragma unroll
            for (int nt = 0; nt < 2; ++nt) {
                int row = nt * 32 + l31;
                int kg = ks * 2 + l5;
                bp[nt] = *(const short8*)(PldsB + row * 512 + ((kg ^ (row & 7)) << 4));
            }
#pragma unroll
            for (int ct = 0; ct < 2; ++ct) {
                int rowc = wv * 64 + ct * 32 + l31;
                short8 av = *(const short8*)(buf + rowc * 32 + l5 * 16);
#pragma unroll
                for (int nt = 0; nt < 2; ++nt)
                    acc3[ct][nt] = mfma32(av, bp[nt], acc3[ct][nt]);
            }
            ++q; sl = (sl == 2) ? 0 : sl + 1;
        }
    }

    // ---- epilogue ----
    LGKM0(); BAR();
    if (t < 64) {
        float zi = 1.0f / Zs[t];
        Zinv[t] = zi;
        match[(size_t)bid * 64 + t] = __expf(Ms[t]) * zi;
    }
    LGKM0(); BAR();
    float zi0 = Zinv[l31], zi1 = Zinv[32 + l31];
    float* rbase = recon + (size_t)b * 2097152 + (size_t)h * 64;
#pragma unroll
    for (int ct = 0; ct < 2; ++ct) {
#pragma unroll
        for (int r = 0; r < 16; ++r) {
            int c = wv * 64 + ct * 32 + (r & 3) + 8 * (r >> 2) + 4 * l5;
            float* rp = rbase + (size_t)c * 4096;
            rp[l31] = acc3[ct][0][r] * zi0;
            rp[32 + l31] = acc3[ct][1][r] * zi1;
        }
    }
}

extern "C" void kernel_launch(void* const* d_in, const int* in_sizes, int n_in,
                              void* d_out, int out_size, void* d_ws, size_t ws_size,
                              hipStream_t stream) {
    (void)in_sizes; (void)n_in; (void)out_size;
    if (ws_size < (size_t)2 * 1024 * 1024) return;

    const float* x = (const float*)d_in[0];
    const float* mem = (const float*)d_in[1];
    float* recon = (float*)d_out;
    float* match = recon + (size_t)16 * 512 * 64 * 64;
    unsigned short* Mn = (unsigned short*)d_ws;
    unsigned short* MnT = Mn + (size_t)K_MEM * C_DIM;

    prep_norm<<<dim3(K_MEM), dim3(256), 0, stream>>>(mem, Mn);
    prep_transpose<<<dim3(128), dim3(256), 0, stream>>>(Mn, MnT);
    fused_attn<<<dim3(1024), dim3(512), 0, stream>>>(x, Mn, MnT, recon, match);
}

// Round 3
// 350.081 us; speedup vs baseline: 1.2562x; 1.2562x over previous
//
#include <hip/hip_runtime.h>

// x: [16, 512, 64, 64] fp32, memory: [1024, 512] fp32
// recon: [16, 512, 64, 64] fp32, match: [16, 64, 64] fp32
#define C_DIM 512
#define K_MEM 1024

typedef __attribute__((ext_vector_type(8))) short short8;     // 8 bf16
typedef __attribute__((ext_vector_type(16))) float f32x16;
typedef __attribute__((ext_vector_type(4))) unsigned int u32x4;

#define LGKM0()  asm volatile("s_waitcnt lgkmcnt(0)" ::: "memory")
#define BAR()    { asm volatile("" ::: "memory"); __builtin_amdgcn_s_barrier(); asm volatile("" ::: "memory"); }

__device__ __forceinline__ unsigned short f2bf(float f) {
    unsigned int u = __builtin_bit_cast(unsigned int, f);
    unsigned int r = (u + 0x7fffu + ((u >> 16) & 1u)) >> 16;  // RNE
    return (unsigned short)r;
}

__device__ __forceinline__ f32x16 mfma32(short8 a, short8 b, f32x16 c) {
    return __builtin_amdgcn_mfma_f32_32x32x16_bf16(a, b, c, 0, 0, 0);
}

// ---------------- prep 1: L2-normalize memory rows -> bf16 Mn[k][c] ----------------
__global__ __launch_bounds__(256)
void prep_norm(const float* __restrict__ mem, unsigned short* __restrict__ Mn) {
    int k = blockIdx.x, t = threadIdx.x;
    const float* row = mem + (size_t)k * C_DIM;
    float2 v = *reinterpret_cast<const float2*>(row + 2 * t);
    float ss = v.x * v.x + v.y * v.y;
#pragma unroll
    for (int off = 32; off >= 1; off >>= 1) ss += __shfl_xor(ss, off);
    __shared__ float wp[4];
    if ((t & 63) == 0) wp[t >> 6] = ss;
    __syncthreads();
    float tot = wp[0] + wp[1] + wp[2] + wp[3];
    float rn = 1.0f / fmaxf(sqrtf(tot), 1e-12f);
    unsigned int pk = (unsigned int)f2bf(v.x * rn) | ((unsigned int)f2bf(v.y * rn) << 16);
    *reinterpret_cast<unsigned int*>(Mn + (size_t)k * C_DIM + 2 * t) = pk;
}

// ---------------- prep 2: transpose Mn[k][c] -> MnT[c][k] ----------------
__global__ __launch_bounds__(256)
void prep_transpose(const unsigned short* __restrict__ Mn, unsigned short* __restrict__ MnT) {
    __shared__ unsigned short tl[64][72];
    int t = threadIdx.x;
    int bk = blockIdx.x & 15, bc = blockIdx.x >> 4;
    int k0 = bk * 64, c0 = bc * 64;
    {
        int kr = t >> 2, gc = (t & 3) * 16;
        const u32x4* src = reinterpret_cast<const u32x4*>(Mn + (size_t)(k0 + kr) * C_DIM + c0 + gc);
        u32x4 a = src[0], b = src[1];
        *reinterpret_cast<u32x4*>(&tl[kr][gc]) = a;
        *reinterpret_cast<u32x4*>(&tl[kr][gc + 8]) = b;
    }
    __syncthreads();
    {
        int cr = t >> 2, gk = (t & 3) * 16;
        unsigned int ow[8];
#pragma unroll
        for (int j = 0; j < 8; ++j)
            ow[j] = (unsigned int)tl[gk + 2 * j][cr] | ((unsigned int)tl[gk + 2 * j + 1][cr] << 16);
        unsigned int* dst = reinterpret_cast<unsigned int*>(MnT + (size_t)(c0 + cr) * K_MEM + k0 + gk);
#pragma unroll
        for (int j = 0; j < 8; ++j) dst[j] = ow[j];
    }
}

// ---------------- fused kernel ----------------
// Per block: one (b,h) line of 64 pixels. 8 waves.
// GEMM1: S^T[k x n] = Mn[k][c] . Fn^T  -- A from GLOBAL (Mn rows), B from LDS (Fn rows).
//   wave = k-octant (32 k), full 64 n.  acc1[nt](nt=n-half): D rows=k(reg), cols=n(lane&31).
// softmax: per-lane over regs + one shfl_xor(32); partials into LDS per (kt,ko).
// GEMM2: recon^T[c x n] = MnT[c][k] . P^T -- A from GLOBAL (MnT rows), B from LDS (Plds rows).
//   wave = c-octant (64 c), full 64 n.  acc3[ct][nt].
__global__ __launch_bounds__(512, 2)
void fused_attn(const float* __restrict__ x,
                const unsigned short* __restrict__ Mn,
                const unsigned short* __restrict__ MnT,
                float* __restrict__ recon,
                float* __restrict__ match) {
    __shared__ alignas(16) char FnB[65536];        // Fn[64 n][64 granules of 16B], gs = g ^ (n&31)
    __shared__ alignas(16) char Plds[2][32768];    // P[64 n][32 granules], gs = g ^ (n&31); dbuf by kt parity
    __shared__ float partS[4][8][64];              // per (kt, k-octant) row sums
    __shared__ float partM[4][8][64];              // per (kt, k-octant) row maxes
    __shared__ float Zinv[64], rnormS[64];

    const int t = threadIdx.x;
    const int bid = blockIdx.x;            // b*64 + h
    const int b = bid >> 6, h = bid & 63;
    const int lane = t & 63, wv = t >> 6;  // 8 waves
    const int l31 = lane & 31, l5 = lane >> 5;
    const int ko = wv;                     // GEMM1 k-octant
    const int cb = wv * 64;                // GEMM2 c-octant base

    // ---- phase 0: load x line into regs, row norms, normalized bf16 -> Fn ----
    {
        float* normpart = (float*)Plds;    // overlay [64][9] (Plds unused until kt0 softmax)
        const int w = lane, cg = wv;       // wave handles c rows cg*64..+64; lane = pixel w
        const float* xp = x + (size_t)b * 2097152 + (size_t)(cg * 64) * 4096 + (size_t)h * 64 + w;
        float xv[64];
#pragma unroll
        for (int i = 0; i < 64; ++i) xv[i] = xp[(size_t)i * 4096];
        float ss = 0.f;
#pragma unroll
        for (int i = 0; i < 64; ++i) ss += xv[i] * xv[i];
        normpart[w * 9 + cg] = ss;
        __syncthreads();
        if (t < 64) {
            float s = 0.f;
#pragma unroll
            for (int j = 0; j < 8; ++j) s += normpart[t * 9 + j];
            rnormS[t] = 1.0f / fmaxf(sqrtf(s), 1e-12f);
        }
        __syncthreads();
        float rn = rnormS[w];
        char* fnrow = FnB + w * 1024;
#pragma unroll
        for (int j = 0; j < 8; ++j) {      // granule j: c = cg*64 + j*8 .. +8
            u32x4 pk4;
#pragma unroll
            for (int p = 0; p < 4; ++p) {
                float v0 = xv[j * 8 + 2 * p] * rn;
                float v1 = xv[j * 8 + 2 * p + 1] * rn;
                pk4[p] = (unsigned int)f2bf(v0) | ((unsigned int)f2bf(v1) << 16);
            }
            int gs = (cg * 8 + j) ^ (w & 31);
            *(u32x4*)(fnrow + (gs << 4)) = pk4;
        }
    }
    __syncthreads();

    f32x16 acc3[2][2];
#pragma unroll
    for (int i = 0; i < 2; ++i)
#pragma unroll
        for (int j = 0; j < 2; ++j)
#pragma unroll
            for (int r = 0; r < 16; ++r) acc3[i][j][r] = 0.f;

    const char* fnR0 = FnB + l31 * 1024;          // n-row l31
    const char* fnR1 = FnB + (32 + l31) * 1024;   // n-row 32+l31

    for (int kt = 0; kt < 4; ++kt) {
        // ================= GEMM1: acc1[nt] over 32 c-steps =================
        const char* aG = (const char*)Mn + (((size_t)(kt * 256 + ko * 32 + l31)) << 10) + (l5 << 4);
        short8 af[2][8];
#pragma unroll
        for (int j = 0; j < 8; ++j) af[0][j] = *(const short8*)(aG + j * 32);

        f32x16 acc1[2];
#pragma unroll
        for (int j = 0; j < 2; ++j)
#pragma unroll
            for (int r = 0; r < 16; ++r) acc1[j][r] = 0.f;

#pragma unroll
        for (int g = 0; g < 4; ++g) {
            if (g < 3) {
#pragma unroll
                for (int j = 0; j < 8; ++j)
                    af[(g + 1) & 1][j] = *(const short8*)(aG + ((g + 1) * 8 + j) * 32);
            }
#pragma unroll
            for (int j = 0; j < 8; ++j) {
                const int s = g * 8 + j;
                const int gsw = (((s << 1) | l5) ^ l31) << 4;
                short8 b0 = *(const short8*)(fnR0 + gsw);
                short8 b1 = *(const short8*)(fnR1 + gsw);
                acc1[0] = mfma32(af[g & 1][j], b0, acc1[0]);
                acc1[1] = mfma32(af[g & 1][j], b1, acc1[1]);
            }
        }

        // prefetch GEMM2 group 0 (global, independent of LDS/barrier)
        const char* aG2 = (const char*)MnT + (((size_t)(cb + l31)) << 11) + (size_t)kt * 512 + (l5 << 4);
        short8 a2[2][2][4];
#pragma unroll
        for (int ct = 0; ct < 2; ++ct)
#pragma unroll
            for (int j = 0; j < 4; ++j)
                a2[0][ct][j] = *(const short8*)(aG2 + ct * 65536 + j * 32);

        // ================= softmax (per-lane; rows k in regs, col n = nt*32+l31) ========
        char* Pb = Plds[kt & 1];
        {
            float pv[2][16];
#pragma unroll
            for (int nt = 0; nt < 2; ++nt)
#pragma unroll
                for (int r = 0; r < 16; ++r) pv[nt][r] = __expf(acc1[nt][r]);
#pragma unroll
            for (int nt = 0; nt < 2; ++nt) {
                float s0 = 0.f, m0 = -3.0e38f;
#pragma unroll
                for (int r = 0; r < 16; ++r) {
                    s0 += pv[nt][r];
                    m0 = fmaxf(m0, acc1[nt][r]);
                }
                s0 += __shfl_xor(s0, 32);                  // combine l5 halves (other 16 k)
                m0 = fmaxf(m0, __shfl_xor(m0, 32));
                if (l5 == 0) {
                    partS[kt][ko][nt * 32 + l31] = s0;
                    partM[kt][ko][nt * 32 + l31] = m0;
                }
            }
            // P -> Plds bf16, pairs (r, r+1) are k-adjacent
#pragma unroll
            for (int nt = 0; nt < 2; ++nt) {
                char* prow = Pb + (nt * 32 + l31) * 512;
#pragma unroll
                for (int rp = 0; rp < 8; ++rp) {
                    const int r = rp * 2;
                    const int klocal = ko * 32 + (r & 3) + 8 * (r >> 2) + 4 * l5;
                    unsigned int pk = (unsigned int)f2bf(pv[nt][r]) |
                                      ((unsigned int)f2bf(pv[nt][r + 1]) << 16);
                    const int gs = (klocal >> 3) ^ l31;
                    *(unsigned int*)(prow + (gs << 4) + (klocal & 7) * 2) = pk;
                }
            }
        }
        LGKM0(); BAR();   // Plds[kt&1] + partials visible; vmcnt (a2 prefetch) stays in flight

        // ================= GEMM2: acc3 += MnT . P^T over 16 k-steps =================
#pragma unroll
        for (int g = 0; g < 4; ++g) {
            if (g < 3) {
#pragma unroll
                for (int ct = 0; ct < 2; ++ct)
#pragma unroll
                    for (int j = 0; j < 4; ++j)
                        a2[(g + 1) & 1][ct][j] =
                            *(const short8*)(aG2 + ct * 65536 + ((g + 1) * 4 + j) * 32);
            }
#pragma unroll
            for (int j = 0; j < 4; ++j) {
                const int ks = g * 4 + j;
                const int gsw = (((ks << 1) | l5) ^ l31) << 4;
                short8 bp0 = *(const short8*)(Pb + l31 * 512 + gsw);
                short8 bp1 = *(const short8*)(Pb + (32 + l31) * 512 + gsw);
                acc3[0][0] = mfma32(a2[g & 1][0][j], bp0, acc3[0][0]);
                acc3[0][1] = mfma32(a2[g & 1][0][j], bp1, acc3[0][1]);
                acc3[1][0] = mfma32(a2[g & 1][1][j], bp0, acc3[1][0]);
                acc3[1][1] = mfma32(a2[g & 1][1][j], bp1, acc3[1][1]);
            }
        }
    }

    // ---- epilogue: Z, match, scaled recon^T store ----
    if (t < 64) {
        float s = 0.f, m = -3.0e38f;
#pragma unroll
        for (int kt = 0; kt < 4; ++kt)
#pragma unroll
            for (int k8 = 0; k8 < 8; ++k8) {
                s += partS[kt][k8][t];
                m = fmaxf(m, partM[kt][k8][t]);
            }
        float zi = 1.0f / s;
        Zinv[t] = zi;
        match[(size_t)bid * 64 + t] = __expf(m) * zi;
    }
    LGKM0(); BAR();

    const float zi0 = Zinv[l31], zi1 = Zinv[32 + l31];
    float* rbase = recon + (size_t)b * 2097152 + (size_t)h * 64;
#pragma unroll
    for (int ct = 0; ct < 2; ++ct) {
#pragma unroll
        for (int r = 0; r < 16; ++r) {
            const int c = cb + ct * 32 + (r & 3) + 8 * (r >> 2) + 4 * l5;
            float* rp = rbase + (size_t)c * 4096;
            rp[l31] = acc3[ct][0][r] * zi0;
            rp[32 + l31] = acc3[ct][1][r] * zi1;
        }
    }
}

extern "C" void kernel_launch(void* const* d_in, const int* in_sizes, int n_in,
                              void* d_out, int out_size, void* d_ws, size_t ws_size,
                              hipStream_t stream) {
    (void)in_sizes; (void)n_in; (void)out_size;
    if (ws_size < (size_t)2 * 1024 * 1024) return;

    const float* x = (const float*)d_in[0];
    const float* mem = (const float*)d_in[1];
    float* recon = (float*)d_out;
    float* match = recon + (size_t)16 * 512 * 64 * 64;
    unsigned short* Mn = (unsigned short*)d_ws;
    unsigned short* MnT = Mn + (size_t)K_MEM * C_DIM;

    prep_norm<<<dim3(K_MEM), dim3(256), 0, stream>>>(mem, Mn);
    prep_transpose<<<dim3(128), dim3(256), 0, stream>>>(Mn, MnT);
    fused_attn<<<dim3(1024), dim3(512), 0, stream>>>(x, Mn, MnT, recon, match);
}